// Round 1
// baseline (1025.646 us; speedup 1.0000x reference)
//
#include <hip/hip_runtime.h>
#include <cstdint>
#include <cstddef>

#define D_MODEL 1024
#define D_FF    4096
#define N_EXPERTS 8
#define TOPK_    2
#define NTOK    8192
#define NSLOT   (NTOK*TOPK_)

// 256^2 8-phase grouped-GEMM tile geometry
#define BM 256
#define BN 256
#define BK 64
#define MAXTILES 72   // sum ceil(count_e/256) <= 16384/256 + 8 = 72

typedef __attribute__((ext_vector_type(8))) short bf16x8;
typedef __attribute__((ext_vector_type(4))) float f32x4;
typedef unsigned int u32;

__device__ __forceinline__ unsigned short f2bf(float f){
  union { float f; u32 u; } v; v.f = f;
  u32 u = v.u;
  u32 r = (u + 0x7FFFu + ((u >> 16) & 1u)) >> 16;
  return (unsigned short)r;
}

__device__ __forceinline__ float bf2f(unsigned short s){
  union { u32 u; float f; } v; v.u = (u32)s << 16; return v.f;
}

// gelu via Abramowitz-Stegun 7.1.26 erf, |err| <= 1.5e-7 abs.
__device__ __forceinline__ float gelu_fast(float x){
  float z = fabsf(x) * 0.70710678118654752f;
  float t = __builtin_amdgcn_rcpf(fmaf(0.3275911f, z, 1.0f));
  float poly = t * (0.254829592f + t * (-0.284496736f + t * (1.421413741f +
               t * (-1.453152027f + t * 1.061405429f))));
  float e = __expf(-z * z);
  float erf_abs = fmaf(-poly, e, 1.0f);
  float erfv = copysignf(erf_abs, x);
  return 0.5f * x * (1.0f + erfv);
}

__device__ __forceinline__ void gload_lds16(const void* g, void* l){
  __builtin_amdgcn_global_load_lds(
      (const __attribute__((address_space(1))) u32*)g,
      (__attribute__((address_space(3))) u32*)l, 16, 0, 0);
}

// ---------------- weight transpose: [E][R][C] fp32 -> [E][C][R] bf16 ----------

__global__ __launch_bounds__(256) void transpose_convert_kernel(
    const float* __restrict__ in, unsigned short* __restrict__ out,
    int R, int C){
  __shared__ float tile[64][65];
  const int e  = blockIdx.z;
  const int c0 = blockIdx.x * 64;
  const int r0 = blockIdx.y * 64;
  const int tid = threadIdx.x;
  const size_t base = (size_t)e * R * C;
  {
    const int r  = tid >> 4;          // 0..15
    const int c4 = (tid & 15) * 4;    // 0..60
    #pragma unroll
    for (int it = 0; it < 4; it++){
      int rr = r + it * 16;
      float4 v = *(const float4*)(in + base + (size_t)(r0 + rr) * C + c0 + c4);
      tile[rr][c4 + 0] = v.x;
      tile[rr][c4 + 1] = v.y;
      tile[rr][c4 + 2] = v.z;
      tile[rr][c4 + 3] = v.w;
    }
  }
  __syncthreads();
  {
    const int c  = tid >> 4;          // 0..15
    const int r4 = (tid & 15) * 4;
    #pragma unroll
    for (int it = 0; it < 4; it++){
      int cc = c + it * 16;
      ushort4 w;
      w.x = f2bf(tile[r4 + 0][cc]);
      w.y = f2bf(tile[r4 + 1][cc]);
      w.z = f2bf(tile[r4 + 2][cc]);
      w.w = f2bf(tile[r4 + 3][cc]);
      *(ushort4*)(out + base + (size_t)(c0 + cc) * R + r0 + r4) = w;
    }
  }
}

// ---------------- router (also converts x -> bf16, single pass) --------------

__global__ __launch_bounds__(64) void router_kernel(
    const float* __restrict__ x,
    const float* __restrict__ Wr,
    const float* __restrict__ br,
    int* __restrict__ counts,
    int* __restrict__ topk_idx,
    float* __restrict__ topk_gate,
    unsigned short* __restrict__ xb){
  const int n = blockIdx.x;
  const int lane = threadIdx.x;      // 64 threads
  const float* xr = x + (size_t)n * D_MODEL;
  unsigned short* xbr = xb + (size_t)n * D_MODEL;
  float acc[N_EXPERTS];
  #pragma unroll
  for (int e = 0; e < N_EXPERTS; e++) acc[e] = 0.f;
  #pragma unroll
  for (int it = 0; it < 4; it++){
    int d = it * 256 + lane * 4;
    float4 v = *(const float4*)(xr + d);
    ushort4 w;
    w.x = f2bf(v.x); w.y = f2bf(v.y); w.z = f2bf(v.z); w.w = f2bf(v.w);
    *(ushort4*)(xbr + d) = w;
    const float* wr = Wr + (size_t)d * N_EXPERTS;
    const float* vv = &v.x;
    #pragma unroll
    for (int j = 0; j < 4; j++)
      #pragma unroll
      for (int e = 0; e < N_EXPERTS; e++)
        acc[e] = fmaf(vv[j], wr[j * N_EXPERTS + e], acc[e]);
  }
  #pragma unroll
  for (int e = 0; e < N_EXPERTS; e++){
    float v = acc[e];
    for (int o = 32; o > 0; o >>= 1) v += __shfl_xor(v, o, 64);
    acc[e] = v;
  }
  if (lane == 0){
    float logits[N_EXPERTS];
    float m = -1e30f;
    #pragma unroll
    for (int e = 0; e < N_EXPERTS; e++){
      logits[e] = acc[e] + br[e];
      m = fmaxf(m, logits[e]);
    }
    float p[N_EXPERTS]; float Z = 0.f;
    #pragma unroll
    for (int e = 0; e < N_EXPERTS; e++){ p[e] = expf(logits[e] - m); Z += p[e]; }
    #pragma unroll
    for (int e = 0; e < N_EXPERTS; e++) p[e] /= Z;
    int i0 = 0;
    #pragma unroll
    for (int e = 1; e < N_EXPERTS; e++) if (p[e] > p[i0]) i0 = e;
    int i1 = (i0 == 0) ? 1 : 0;
    #pragma unroll
    for (int e = 0; e < N_EXPERTS; e++){
      if (e == i0) continue;
      if (p[e] > p[i1]) i1 = e;
    }
    float s = p[i0] + p[i1] + 1e-9f;
    topk_idx[n * 2 + 0] = i0;
    topk_idx[n * 2 + 1] = i1;
    topk_gate[n * 2 + 0] = p[i0] / s;
    topk_gate[n * 2 + 1] = p[i1] / s;
    atomicAdd(&counts[i0], 1);
    atomicAdd(&counts[i1], 1);
  }
}

// ---------------- bookkeeping: offsets + tile table, parallel ----------------

__global__ __launch_bounds__(256) void prefix_kernel(
    const int* __restrict__ counts,
    int* __restrict__ offsets,
    int* __restrict__ cursor,
    int* __restrict__ tile_e,
    int* __restrict__ tile_m){
  __shared__ int scnt[N_EXPERTS];
  __shared__ int soff[N_EXPERTS];
  const int tid = threadIdx.x;
  if (tid < N_EXPERTS) scnt[tid] = counts[tid];
  __syncthreads();
  if (tid == 0){
    int o = 0;
    for (int e = 0; e < N_EXPERTS; e++){ soff[e] = o; o += scnt[e]; }
  }
  __syncthreads();
  if (tid < N_EXPERTS){ offsets[tid] = soff[tid]; cursor[tid] = soff[tid]; }
  if (tid < MAXTILES){
    int t = tid, te = -1, tm = 0, acc = 0;
    #pragma unroll
    for (int e = 0; e < N_EXPERTS; e++){
      int nt = (scnt[e] + BM - 1) / BM;
      if (te < 0 && t < acc + nt){ te = e; tm = t - acc; }
      acc += nt;
    }
    tile_e[tid] = te; tile_m[tid] = tm;
  }
}

__global__ void assign_kernel(const int* __restrict__ topk_idx,
                              const float* __restrict__ topk_gate,
                              int* __restrict__ cursor,
                              int* __restrict__ bucket_token,
                              float* __restrict__ bucket_gate,
                              int* __restrict__ slot_of){
  int n = blockIdx.x * blockDim.x + threadIdx.x;
  if (n >= NTOK) return;
  #pragma unroll
  for (int k = 0; k < TOPK_; k++){
    int e = topk_idx[n * 2 + k];
    float g = topk_gate[n * 2 + k];
    int s = atomicAdd(&cursor[e], 1);
    bucket_token[s] = n;
    bucket_gate[s] = g;
    slot_of[n * 2 + k] = s;
  }
}

// ---------------- grouped GEMM, 256^2 tile, 8-phase counted-vmcnt schedule ----
//
// Schedule ledger (per K-tile t, buffer cur = t&1; tile = 4 half-tiles
// h0=A[0:128), h1=A[128:256), h2=B[0:128), h3=B[128:256), 2 gloads each):
//   P0: ds a(m0-3)+b(n0-1) of t | stage (t+1).h1 | bar | mfma Q(0,0) | bar
//   P1: ds b(n2-3)             | stage (t+1).h2 | bar | mfma Q(0,2) | bar
//   P2: ds a(m4-7)             | stage (t+1).h3 | bar | mfma Q(1,0) | bar
//   P3: stage (t+2).h0 | mfma Q(1,2) | vmcnt(2) | bar
// All ds_reads of tile t complete by P2's closing barrier (MFMA dataflow
// lgkm waits), so P3's overwrite of rows 0-127 of the CURRENT buffer is
// write-safe. vmcnt(2) leaves only (t+2).h0's 2 loads in flight across the
// barrier (never drain to 0 in the main loop). Raw s_barrier (no implicit
// vmcnt(0) drain); XOR column swizzle (bank-conflict-free, PMC-verified 0
// in the 128^2 predecessor).

#define BARR do { asm volatile("" ::: "memory"); \
                  __builtin_amdgcn_s_barrier(); \
                  asm volatile("" ::: "memory"); } while(0)
#define VMW(n) asm volatile("s_waitcnt vmcnt(" #n ")" ::: "memory")

// stage A half-tile (half=0: rows 0-127, half=1: rows 128-255) at k offset
#define SA_(bufi, half, k) do { \
  gload_lds16(asrc[2*(half)]   + (k), &As[bufi][(2*(half))*64   + (tid>>3)][(tid&7)*8]); \
  gload_lds16(asrc[2*(half)+1] + (k), &As[bufi][(2*(half)+1)*64 + (tid>>3)][(tid&7)*8]); \
} while(0)
#define SB_(bufi, half, k) do { \
  gload_lds16(bsrc[2*(half)]   + (k), &Bs[bufi][(2*(half))*64   + (tid>>3)][(tid&7)*8]); \
  gload_lds16(bsrc[2*(half)+1] + (k), &Bs[bufi][(2*(half)+1)*64 + (tid>>3)][(tid&7)*8]); \
} while(0)

#define LDA_(bufi, ih) do { \
  _Pragma("unroll") \
  for (int i_ = 0; i_ < 4; i_++){ \
    a[i_][0] = *(const bf16x8*)&As[bufi][wm + ((ih)*4 + i_)*16 + fm][ck0]; \
    a[i_][1] = *(const bf16x8*)&As[bufi][wm + ((ih)*4 + i_)*16 + fm][ck1]; \
  } \
} while(0)
#define LDB_(bufi, j0) do { \
  _Pragma("unroll") \
  for (int j_ = 0; j_ < 2; j_++){ \
    b[(j0)+j_][0] = *(const bf16x8*)&Bs[bufi][wn + ((j0)+j_)*16 + fm][ck0]; \
    b[(j0)+j_][1] = *(const bf16x8*)&Bs[bufi][wn + ((j0)+j_)*16 + fm][ck1]; \
  } \
} while(0)

#define MF_(ih, j0) do { \
  __builtin_amdgcn_s_setprio(1); \
  _Pragma("unroll") \
  for (int i_ = 0; i_ < 4; i_++) \
    _Pragma("unroll") \
    for (int j_ = 0; j_ < 2; j_++){ \
      acc[(ih)*4+i_][(j0)+j_] = __builtin_amdgcn_mfma_f32_16x16x32_bf16(a[i_][0], b[(j0)+j_][0], acc[(ih)*4+i_][(j0)+j_], 0, 0, 0); \
      acc[(ih)*4+i_][(j0)+j_] = __builtin_amdgcn_mfma_f32_16x16x32_bf16(a[i_][1], b[(j0)+j_][1], acc[(ih)*4+i_][(j0)+j_], 0, 0, 0); \
    } \
  __builtin_amdgcn_s_setprio(0); \
} while(0)

#define TILE_FULL(bufi, kn, kn2) do { \
  LDA_(bufi,0); LDB_(bufi,0); SA_(1-(bufi),1,(kn)); BARR; MF_(0,0); BARR; \
  LDB_(bufi,2);               SB_(1-(bufi),0,(kn)); BARR; MF_(0,2); BARR; \
  LDA_(bufi,1);               SB_(1-(bufi),1,(kn)); BARR; MF_(1,0); BARR; \
  SA_((bufi),0,(kn2)); MF_(1,2); VMW(2); BARR; \
} while(0)

#define TILE_TAIL0(bufi, kn) do { \
  LDA_(bufi,0); LDB_(bufi,0); SA_(1-(bufi),1,(kn)); BARR; MF_(0,0); BARR; \
  LDB_(bufi,2);               SB_(1-(bufi),0,(kn)); BARR; MF_(0,2); BARR; \
  LDA_(bufi,1);               SB_(1-(bufi),1,(kn)); BARR; MF_(1,0); BARR; \
  MF_(1,2); VMW(0); BARR; \
} while(0)

#define TILE_TAIL1(bufi) do { \
  LDA_(bufi,0); LDB_(bufi,0); BARR; MF_(0,0); BARR; \
  LDB_(bufi,2);               BARR; MF_(0,2); BARR; \
  LDA_(bufi,1);               BARR; MF_(1,0); BARR; \
  MF_(1,2); \
} while(0)

// MODE 0: gemm1  h = gelu(xb[token] @ W1t + b1)     (KDIM=1024, NDIM=4096)
// MODE 1: gemm2  y = g * (hb[slot] @ W2t + b2)      (KDIM=4096, NDIM=1024)
template<int KDIM, int NDIM, int MODE>
__global__ __launch_bounds__(512, 2) void moe_gemm_kernel(
    const unsigned short* __restrict__ A,
    const unsigned short* __restrict__ Wt,
    const float* __restrict__ bias_g,
    const int* __restrict__ bucket_token,
    const float* __restrict__ bucket_gate,
    const int* __restrict__ offsets,
    const int* __restrict__ counts,
    const int* __restrict__ tile_e,
    const int* __restrict__ tile_m,
    unsigned short* __restrict__ out){
  const int e = tile_e[blockIdx.y];
  if (e < 0) return;
  const int mtile = tile_m[blockIdx.y];
  const int ntile = blockIdx.x;
  const int count = counts[e];
  const int off = offsets[e];

  __shared__ unsigned short As[2][BM][BK];   // 64 KB
  __shared__ unsigned short Bs[2][BN][BK];   // 64 KB

  const int tid  = threadIdx.x;
  const int lane = tid & 63;
  const int wave = tid >> 6;          // 8 waves: 2 (M) x 4 (N)
  const int wm = (wave >> 2) * 128;
  const int wn = (wave & 3) * 64;
  const int fm = lane & 15;
  // swizzled k-column element offsets for the two k-subtiles (kk=0,32)
  const int ck0 = (((lane >> 4)    ) ^ (lane & 7)) * 8;
  const int ck1 = (((lane >> 4) + 4) ^ (lane & 7)) * 8;
  // staging: thread covers row (c*64 + tid>>3), LDS colgrp tid&7,
  // global colgrp (tid&7)^((tid>>3)&7)  [LDS[r][c] = global[r][c ^ (r&7)]]
  const int cg = ((tid & 7) ^ ((tid >> 3) & 7)) * 8;

  const unsigned short* asrc[4];
  const unsigned short* bsrc[4];
  #pragma unroll
  for (int c = 0; c < 4; c++){
    int m = mtile * BM + c * 64 + (tid >> 3);
    int mm = min(m, count - 1);
    size_t arow = (MODE == 0) ? (size_t)bucket_token[off + mm] : (size_t)(off + mm);
    asrc[c] = A + arow * KDIM + cg;
    bsrc[c] = Wt + ((size_t)e * NDIM + (size_t)ntile * BN + c * 64 + (tid >> 3)) * KDIM + cg;
  }

  const f32x4 zero = {0.f, 0.f, 0.f, 0.f};
  f32x4 acc[8][4];
  #pragma unroll
  for (int i = 0; i < 8; i++)
    #pragma unroll
    for (int j = 0; j < 4; j++) acc[i][j] = zero;

  bf16x8 a[4][2], b[4][2];

  // ---- prologue: tile0 fully, tile1.h0; wait tile0 (leave 2 in flight) ----
  SA_(0,0,0); SA_(0,1,0); SB_(0,0,0); SB_(0,1,0);
  SA_(1,0,BK);
  VMW(2); BARR;

  int k = 0;
  #pragma unroll 1
  for (int tp = 0; tp < KDIM/BK/2 - 1; ++tp){
    TILE_FULL(0, k + BK,     k + 2*BK);
    TILE_FULL(1, k + 2*BK,   k + 3*BK);
    k += 2*BK;
  }
  // tail pair: tiles NT-2 (buf0), NT-1 (buf1)
  TILE_TAIL0(0, k + BK);
  TILE_TAIL1(1);

  // ---- epilogue ----
  const float* bias = bias_g + (size_t)e * NDIM + (size_t)ntile * BN;
  float bj[4];
  #pragma unroll
  for (int j = 0; j < 4; j++) bj[j] = bias[wn + j * 16 + fm];

  #pragma unroll
  for (int i = 0; i < 8; i++){
    #pragma unroll
    for (int r = 0; r < 4; r++){
      int mrel = wm + i * 16 + (lane >> 4) * 4 + r;
      int m = mtile * BM + mrel;
      if (m >= count) continue;
      int slot = off + m;
      unsigned short* orow = out + (size_t)slot * NDIM + (size_t)ntile * BN;
      if constexpr (MODE == 0){
        #pragma unroll
        for (int j = 0; j < 4; j++){
          float v = acc[i][j][r] + bj[j];
          orow[wn + j * 16 + fm] = f2bf(gelu_fast(v));
        }
      } else {
        float g = bucket_gate[slot];
        #pragma unroll
        for (int j = 0; j < 4; j++){
          float v = g * (acc[i][j][r] + bj[j]);
          orow[wn + j * 16 + fm] = f2bf(v);
        }
      }
    }
  }
}

// ---------------- combine: out[t] = y[slot0(t)] + y[slot1(t)] ----------------

__global__ __launch_bounds__(256) void combine_kernel(
    const unsigned short* __restrict__ y,
    const int* __restrict__ slot_of,
    float* __restrict__ out){
  const int t = blockIdx.x;
  const int d = threadIdx.x * 4;
  const int s0 = slot_of[t * 2 + 0];
  const int s1 = slot_of[t * 2 + 1];
  uint2 a = *(const uint2*)(y + (size_t)s0 * D_MODEL + d);
  uint2 b = *(const uint2*)(y + (size_t)s1 * D_MODEL + d);
  float4 r;
  r.x = bf2f((unsigned short)(a.x & 0xffff)) + bf2f((unsigned short)(b.x & 0xffff));
  r.y = bf2f((unsigned short)(a.x >> 16))    + bf2f((unsigned short)(b.x >> 16));
  r.z = bf2f((unsigned short)(a.y & 0xffff)) + bf2f((unsigned short)(b.y & 0xffff));
  r.w = bf2f((unsigned short)(a.y >> 16))    + bf2f((unsigned short)(b.y >> 16));
  *(float4*)(out + (size_t)t * D_MODEL + d) = r;
}

// ---------------- launch ----------------

extern "C" void kernel_launch(void* const* d_in, const int* in_sizes, int n_in,
                              void* d_out, int out_size, void* d_ws, size_t ws_size,
                              hipStream_t stream) {
  (void)in_sizes; (void)n_in; (void)ws_size; (void)out_size;
  const float* x  = (const float*)d_in[0];
  const float* Wr = (const float*)d_in[1];
  const float* br = (const float*)d_in[2];
  const float* W1 = (const float*)d_in[3];
  const float* b1 = (const float*)d_in[4];
  const float* W2 = (const float*)d_in[5];
  const float* b2 = (const float*)d_in[6];
  float* out = (float*)d_out;

  char* ws = (char*)d_ws;
  size_t p = 0;
  auto alloc = [&](size_t bytes) -> void* {
    void* r = ws + p;
    p = (p + bytes + 255) & ~(size_t)255;
    return r;
  };

  int*   counts       = (int*)  alloc(N_EXPERTS * sizeof(int));
  int*   offsets      = (int*)  alloc(N_EXPERTS * sizeof(int));
  int*   cursor       = (int*)  alloc(N_EXPERTS * sizeof(int));
  int*   tile_e       = (int*)  alloc(MAXTILES * sizeof(int));
  int*   tile_m       = (int*)  alloc(MAXTILES * sizeof(int));
  int*   topk_idx     = (int*)  alloc((size_t)NTOK * 2 * sizeof(int));
  float* topk_gate    = (float*)alloc((size_t)NTOK * 2 * sizeof(float));
  int*   bucket_token = (int*)  alloc((size_t)NSLOT * sizeof(int));
  float* bucket_gate  = (float*)alloc((size_t)NSLOT * sizeof(float));
  int*   slot_of      = (int*)  alloc((size_t)NTOK * 2 * sizeof(int));
  unsigned short* xb  = (unsigned short*)alloc((size_t)NTOK * D_MODEL * 2);
  unsigned short* W1t = (unsigned short*)alloc((size_t)N_EXPERTS * D_MODEL * D_FF * 2);
  unsigned short* W2t = (unsigned short*)alloc((size_t)N_EXPERTS * D_MODEL * D_FF * 2);
  unsigned short* hb  = (unsigned short*)alloc((size_t)NSLOT * D_FF * 2);
  // y (bf16, 32 MB) aliases W1t (64 MB): W1t is dead once gemm1 completes.
  unsigned short* y = W1t;

  hipMemsetAsync(counts, 0, N_EXPERTS * sizeof(int), stream);

  // Transposes FIRST so nothing streams between gemm1 and gemm2 (keeps h
  // L3-resident for gemm2), and gemm1 reads recently-written xb/W1t.
  transpose_convert_kernel<<<dim3(D_MODEL / 64, D_FF / 64, N_EXPERTS), 256, 0, stream>>>(
      W2, W2t, D_FF, D_MODEL);
  transpose_convert_kernel<<<dim3(D_FF / 64, D_MODEL / 64, N_EXPERTS), 256, 0, stream>>>(
      W1, W1t, D_MODEL, D_FF);
  router_kernel<<<NTOK, 64, 0, stream>>>(x, Wr, br, counts, topk_idx, topk_gate, xb);
  prefix_kernel<<<1, 256, 0, stream>>>(counts, offsets, cursor, tile_e, tile_m);
  assign_kernel<<<NTOK / 256, 256, 0, stream>>>(topk_idx, topk_gate, cursor,
                                                bucket_token, bucket_gate, slot_of);
  moe_gemm_kernel<D_MODEL, D_FF, 0><<<dim3(D_FF / BN, MAXTILES), 512, 0, stream>>>(
      xb, W1t, b1, bucket_token, nullptr, offsets, counts, tile_e, tile_m, hb);
  moe_gemm_kernel<D_FF, D_MODEL, 1><<<dim3(D_MODEL / BN, MAXTILES), 512, 0, stream>>>(
      hb, W2t, b2, nullptr, bucket_gate, offsets, counts, tile_e, tile_m, y);
  combine_kernel<<<NTOK, 256, 0, stream>>>(y, slot_of, out);
}